// Round 4
// baseline (59.540 us; speedup 1.0000x reference)
//
#include <hip/hip_runtime.h>

#define NREG   20
#define EDIM   768
#define DVOL   64
#define HVOL   512
#define WVOL   512
#define HW_    (HVOL * WVOL)
#define DHW_   (DVOL * HVOL * WVOL)
#define NPATCH 16384
#define BTOT   2
#define PROTO_N (NREG * EDIM)            // 15360
#define RF_N    (BTOT * PROTO_N)         // 30720 floats (output 0)
#define TOTAL_PATCHES (BTOT * NPATCH)    // 32768

// 16-byte load with only 4-byte alignment guarantee.
struct __attribute__((packed, aligned(4))) int4p { int x, y, z, w; };

// ---------------------------------------------------------------------------
// One wave per patch. Lane = (yy = lane>>2) x (xl4 = lane&3).
// ALL 4 z-slice gathers issue unconditionally back-to-back (one latency
// exposure); z/y/x clipping folded into per-voxel AND-masks (invalid -> 0,
// region 0 is never counted). Packed 8-bit histogram, 3-step butterfly,
// LDS finish. Blocks 0..119 also copy the prototype broadcast (output 0).
// ---------------------------------------------------------------------------
__global__ __launch_bounds__(256) void assign_kernel(
    const int*   __restrict__ seg,
    const float* __restrict__ coords,
    const float* __restrict__ proto,
    float*       __restrict__ out)
{
    __shared__ unsigned smem[4][8][5];

    // fused output 0: region_features = broadcast prototypes (120 blocks)
    if (blockIdx.x < RF_N / 256) {
        const int i = blockIdx.x * 256 + threadIdx.x;
        out[i] = proto[i >= PROTO_N ? i - PROTO_N : i];
    }

    const int lane  = threadIdx.x & 63;
    const int wave  = threadIdx.x >> 6;
    const int patch = blockIdx.x * 4 + wave;          // grid = 8192 -> exact
    const int b     = patch >> 14;

    // --- crop box, exactly mirroring the reference float math --------------
    const float c0 = coords[patch * 3 + 0] * 64.0f;   // z
    const float c1 = coords[patch * 3 + 1] * 512.0f;  // y
    const float c2 = coords[patch * 3 + 2] * 512.0f;  // x

    const int sz = (int)fmaxf(0.0f,   floorf(c0 - 2.0f));
    const int ez = (int)fminf(64.0f,  floorf(c0 + 2.0f));
    const int sy = (int)fmaxf(0.0f,   floorf(c1 - 8.0f));
    const int ey = (int)fminf(512.0f, floorf(c1 + 8.0f));
    const int sx = (int)fmaxf(0.0f,   floorf(c2 - 8.0f));
    const int ex = (int)fminf(512.0f, floorf(c2 + 8.0f));

    // --- per-lane constants ------------------------------------------------
    const int xl4  = lane & 3;                 // which 4-int chunk of the row
    const int yy   = lane >> 2;                // y offset 0..15
    const int p_lo = sx + 4 * xl4;             // intended chunk start
    const int st   = min(p_lo, WVOL - 4);      // clamped load start (in-row)
    const int yi   = sy + yy;
    const unsigned vy = (yi < ey) ? 0xFFFFFFFFu : 0u;
    const int yiC  = min(yi, HVOL - 1);
    const int rowbase = b * DHW_ + yiC * WVOL + st;

    // y+x validity masks (z-independent part)
    unsigned vm[4];
#pragma unroll
    for (int j = 0; j < 4; ++j) {
        const int pos = st + j;
        vm[j] = (pos >= p_lo && pos < ex) ? vy : 0u;
    }

    // --- 4 unconditional gathers, issued back-to-back ----------------------
    int4p q0, q1, q2, q3;
    {
        const int z0 = min(sz + 0, DVOL - 1) * HW_;
        const int z1 = min(sz + 1, DVOL - 1) * HW_;
        const int z2 = min(sz + 2, DVOL - 1) * HW_;
        const int z3 = min(sz + 3, DVOL - 1) * HW_;
        q0 = *(const int4p*)(seg + rowbase + z0);
        q1 = *(const int4p*)(seg + rowbase + z1);
        q2 = *(const int4p*)(seg + rowbase + z2);
        q3 = *(const int4p*)(seg + rowbase + z3);
    }

    // packed 8-bit counters: cc[k] holds regions 4k..4k+3 (0-based region m)
    unsigned cc[5] = {0u, 0u, 0u, 0u, 0u};

#pragma unroll
    for (int z = 0; z < 4; ++z) {
        const unsigned zm = (sz + z < ez) ? 0xFFFFFFFFu : 0u;
        const int4p qz = (z == 0) ? q0 : (z == 1) ? q1 : (z == 2) ? q2 : q3;
        const int vals[4] = {qz.x, qz.y, qz.z, qz.w};
#pragma unroll
        for (int j = 0; j < 4; ++j) {
            const int v = vals[j] & (int)(vm[j] & zm);  // invalid -> 0
            const int t = v - 1;                        // -1 if not counted
            const unsigned inc = 1u << ((t & 3) << 3);
            const int qk = t >> 2;                      // -1 matches no k
#pragma unroll
            for (int k = 0; k < 5; ++k)
                cc[k] += (qk == k) ? inc : 0u;
        }
    }

    // --- 3-step packed butterfly (groups of 8 lanes; max 128/field) --------
#pragma unroll
    for (int off = 1; off < 8; off <<= 1) {
#pragma unroll
        for (int k = 0; k < 5; ++k)
            cc[k] += (unsigned)__shfl_xor((int)cc[k], off);
    }

    // one lane per 8-group stages its 5 packed regs to LDS
    if ((lane & 7) == 0) {
#pragma unroll
        for (int k = 0; k < 5; ++k)
            smem[wave][lane >> 3][k] = cc[k];
    }
    __syncthreads();

    // --- finish: lanes 0..19 sum their region's byte across the 8 groups ---
    const float nz = (float)max(ez - sz, 0);
    const float ny = (float)max(ey - sy, 0);
    const float nx = (float)max(ex - sx, 0);
    const float numel = nz * ny * nx;
    const float denom = fmaxf(numel, 1.0f);

    unsigned cnt = 0u;
    if (lane < NREG) {
        const int k  = lane >> 2;
        const int sh = (lane & 3) * 8;
#pragma unroll
        for (int g = 0; g < 8; ++g)
            cnt += (smem[wave][g][k] >> sh) & 0xFFu;
    }

    // total over all regions: 5-step butterfly over lanes 0..31 (>=20 are 0)
    unsigned tot = cnt;
#pragma unroll
    for (int off = 1; off < 32; off <<= 1)
        tot += (unsigned)__shfl_xor((int)tot, off);

    if (lane < NREG) {
        const float s = (float)tot / denom + (float)NREG * 1e-6f;
        const float a = (float)cnt / denom + 1e-6f;
        out[RF_N + patch * NREG + lane] = a / s;
    }
}

// ---------------------------------------------------------------------------
extern "C" void kernel_launch(void* const* d_in, const int* in_sizes, int n_in,
                              void* d_out, int out_size, void* d_ws, size_t ws_size,
                              hipStream_t stream)
{
    const int*   seg    = (const int*)d_in[0];
    const float* coords = (const float*)d_in[1];
    const float* proto  = (const float*)d_in[2];
    float*       out    = (float*)d_out;

    hipLaunchKernelGGL(assign_kernel, dim3(TOTAL_PATCHES / 4), dim3(256), 0, stream,
                       seg, coords, proto, out);
}